// Round 2
// baseline (1078.113 us; speedup 1.0000x reference)
//
#include <hip/hip_runtime.h>
#include <hip/hip_bf16.h>
#include <math.h>

// Problem constants (CausalSelfAttention: B=4, S=2048, Dm=2048, H=16, Hd=128)
// Inputs/outputs are FP32 (per reference); compute in bf16 MFMA w/ fp32 accum.
#define SEQ   2048
#define DM    2048
#define NH    16
#define HD    128
#define MROWS 8192   // B*S

typedef __bf16 bf16x8 __attribute__((ext_vector_type(8)));
typedef float  f32x4  __attribute__((ext_vector_type(4)));

#define MFMA16(a, b, c) __builtin_amdgcn_mfma_f32_16x16x32_bf16((a), (b), (c), 0, 0, 0)

__device__ __forceinline__ void g2l16(const void* g, void* l) {
    __builtin_amdgcn_global_load_lds(
        (const __attribute__((address_space(1))) void*)g,
        (__attribute__((address_space(3))) void*)l, 16, 0, 0);
}

// ---------------------------------------------------------------------------
// Elementwise fp32 -> bf16 convert (8 elements / thread, 16B stores)
// ---------------------------------------------------------------------------
__global__ void cvt_f32_bf16(const float* __restrict__ src, __bf16* __restrict__ dst,
                             size_t n) {
    const size_t i0 = ((size_t)blockIdx.x * blockDim.x + threadIdx.x) * 8;
    if (i0 + 7 >= n) {
        for (size_t i = i0; i < n; ++i) dst[i] = (__bf16)src[i];
        return;
    }
    f32x4 a = *(const f32x4*)(src + i0);
    f32x4 b = *(const f32x4*)(src + i0 + 4);
    bf16x8 o;
#pragma unroll
    for (int j = 0; j < 4; ++j) { o[j] = (__bf16)a[j]; o[4 + j] = (__bf16)b[j]; }
    *(bf16x8*)(dst + i0) = o;
}

// ---------------------------------------------------------------------------
// Transpose + convert: dst[c][r] = (bf16)src[r][c], src fp32 [R,C]
// ---------------------------------------------------------------------------
__global__ void transpose_f32_to_bf16(const float* __restrict__ src,
                                      __bf16* __restrict__ dst, int R, int C) {
    __shared__ float t[32][33];
    const int r0 = blockIdx.y * 32, c0 = blockIdx.x * 32;
    for (int i = threadIdx.y; i < 32; i += 8)
        t[i][threadIdx.x] = src[(size_t)(r0 + i) * C + c0 + threadIdx.x];
    __syncthreads();
    for (int i = threadIdx.y; i < 32; i += 8)
        dst[(size_t)(c0 + i) * R + r0 + threadIdx.x] = (__bf16)t[threadIdx.x][i];
}

// ---------------------------------------------------------------------------
// Tiled transpose, bf16: dst[c][r] = src[r][c], batched over blockIdx.z
// ---------------------------------------------------------------------------
__global__ void transpose_bf16(const __bf16* __restrict__ src, __bf16* __restrict__ dst,
                               int R, int C, long sstride, long dstride) {
    __shared__ __bf16 t[32][33];
    src += (size_t)blockIdx.z * sstride;
    dst += (size_t)blockIdx.z * dstride;
    const int r0 = blockIdx.y * 32, c0 = blockIdx.x * 32;
    for (int i = threadIdx.y; i < 32; i += 8)
        t[i][threadIdx.x] = src[(size_t)(r0 + i) * C + c0 + threadIdx.x];
    __syncthreads();
    for (int i = threadIdx.y; i < 32; i += 8)
        dst[(size_t)(c0 + i) * R + r0 + threadIdx.x] = t[threadIdx.x][i];
}

// ---------------------------------------------------------------------------
// GEMM (m97 structure): C[M,N] = A[M,K] * Bt[N,K]^T + bias[n]
// 128x128 tile, BK=32, 4 waves in 2x2, each wave 64x64 via 4x4 MFMA 16x16x32.
// MODE 0: write bf16 to [B,H,S,D] (QKV remap).  MODE 1: write fp32 flat [M,N].
// ---------------------------------------------------------------------------
template <int MODE>
__global__ __launch_bounds__(256) void gemm_bt(const __bf16* __restrict__ A,
                                               const __bf16* __restrict__ Bt,
                                               const float* __restrict__ bias,
                                               void* __restrict__ Cout_) {
    constexpr int K = DM, N = DM;
    __shared__ __bf16 As[128 * 32];
    __shared__ __bf16 Bs[128 * 32];
    const int tid  = threadIdx.x;
    const int wave = tid >> 6, lane = tid & 63;
    const int quad = lane >> 4, l16 = lane & 15;
    const int bm = blockIdx.x * 128, bn = blockIdx.y * 128;
    const int wm = (wave >> 1) * 64, wn = (wave & 1) * 64;

    f32x4 acc[4][4];
#pragma unroll
    for (int i = 0; i < 4; ++i)
#pragma unroll
        for (int j = 0; j < 4; ++j) acc[i][j] = (f32x4){0.f, 0.f, 0.f, 0.f};

    for (int k0 = 0; k0 < K; k0 += 32) {
        __syncthreads();
#pragma unroll
        for (int j = 0; j < 2; ++j) {
            const int region = wave + 4 * j;              // 0..7, 1KB regions
            const int row    = region * 16 + (lane >> 2); // 0..127
            const int kc     = lane & 3;                  // 16B chunk in 64B row
            g2l16(A  + (size_t)(bm + row) * K + k0 + kc * 8, As + region * 512);
            g2l16(Bt + (size_t)(bn + row) * K + k0 + kc * 8, Bs + region * 512);
        }
        __syncthreads();

        bf16x8 af[4], bf[4];
#pragma unroll
        for (int i = 0; i < 4; ++i)
            af[i] = *(const bf16x8*)(As + (wm + i * 16 + l16) * 32 + quad * 8);
#pragma unroll
        for (int j = 0; j < 4; ++j)
            bf[j] = *(const bf16x8*)(Bs + (wn + j * 16 + l16) * 32 + quad * 8);
#pragma unroll
        for (int i = 0; i < 4; ++i)
#pragma unroll
            for (int j = 0; j < 4; ++j) acc[i][j] = MFMA16(af[i], bf[j], acc[i][j]);
    }

#pragma unroll
    for (int i = 0; i < 4; ++i)
#pragma unroll
        for (int j = 0; j < 4; ++j)
#pragma unroll
            for (int r = 0; r < 4; ++r) {
                const int m = bm + wm + i * 16 + quad * 4 + r;
                const int n = bn + wn + j * 16 + l16;
                const float v = acc[i][j][r] + bias[n];
                if (MODE == 0) {
                    const int b = m >> 11, s = m & (SEQ - 1);
                    const int h = n >> 7, d = n & (HD - 1);
                    ((__bf16*)Cout_)[((size_t)((b * NH + h) * SEQ + s)) * HD + d] = (__bf16)v;
                } else {
                    ((float*)Cout_)[(size_t)m * N + n] = v;
                }
            }
}

// ---------------------------------------------------------------------------
// Flash attention fwd, causal. Q,K: [B,H,S,D] bf16; Vt: [B,H,D,S] bf16.
// Block = 64 queries (4 waves x 16 rows each), K-tiles of 64 keys.
// Output O: [B,S,H*D] bf16 (row-major for the final GEMM).
// ---------------------------------------------------------------------------
__global__ __launch_bounds__(256) void fa_fwd(const __bf16* __restrict__ Q,
                                              const __bf16* __restrict__ Kg,
                                              const __bf16* __restrict__ Vt,
                                              __bf16* __restrict__ O) {
    __shared__ __bf16 Ks[64 * 128];   // [key][d]     16KB
    __shared__ __bf16 Vs[128 * 64];   // [d][key]     16KB
    __shared__ __bf16 Ps[4][16 * 64]; // per-wave P   8KB
    const int tid  = threadIdx.x;
    const int wave = tid >> 6, lane = tid & 63;
    const int quad = lane >> 4, l16 = lane & 15;
    const int bh = blockIdx.y;        // b*NH + h
    const int q0 = blockIdx.x * 64;

    // Q fragments held in registers: each wave owns 16 query rows
    bf16x8 qf[4];
    const __bf16* qrow = Q + (size_t)(bh * SEQ + q0 + wave * 16 + l16) * HD;
#pragma unroll
    for (int kc = 0; kc < 4; ++kc) qf[kc] = *(const bf16x8*)(qrow + kc * 32 + quad * 8);

    float m_r[4], l_r[4];
    f32x4 oacc[8];
#pragma unroll
    for (int r = 0; r < 4; ++r) { m_r[r] = -INFINITY; l_r[r] = 0.f; }
#pragma unroll
    for (int ot = 0; ot < 8; ++ot) oacc[ot] = (f32x4){0.f, 0.f, 0.f, 0.f};

    const int ntiles = q0 / 64 + 1;
    for (int kt = 0; kt < ntiles; ++kt) {
        const int k0 = kt * 64;
        __syncthreads();
#pragma unroll
        for (int j = 0; j < 4; ++j) {
            const int reg = wave * 4 + j;                 // 16 x 1KB regions
            const int krow = reg * 4 + (lane >> 4);       // K: 4 rows (256B) / region
            g2l16(Kg + (size_t)(bh * SEQ + k0 + krow) * HD + (lane & 15) * 8, Ks + reg * 512);
            const int drow = reg * 8 + (lane >> 3);       // Vt: 8 rows (128B) / region
            g2l16(Vt + (size_t)(bh * HD + drow) * SEQ + k0 + (lane & 7) * 8, Vs + reg * 512);
        }
        __syncthreads();

        // S = Q K^T * scale   (C-layout: row=quad*4+r query, col=l16 key)
        f32x4 sc[4];
#pragma unroll
        for (int t = 0; t < 4; ++t) {
            f32x4 a = (f32x4){0.f, 0.f, 0.f, 0.f};
#pragma unroll
            for (int kc = 0; kc < 4; ++kc) {
                bf16x8 kf = *(const bf16x8*)(Ks + (t * 16 + l16) * 128 + kc * 32 + quad * 8);
                a = MFMA16(qf[kc], kf, a);
            }
#pragma unroll
            for (int r = 0; r < 4; ++r) sc[t][r] = a[r] * 0.08838834764831845f;
        }
        // causal mask (only the diagonal tile needs it)
        if (k0 == q0) {
#pragma unroll
            for (int t = 0; t < 4; ++t)
#pragma unroll
                for (int r = 0; r < 4; ++r) {
                    const int key = k0 + t * 16 + l16;
                    const int qr  = q0 + wave * 16 + quad * 4 + r;
                    if (key > qr) sc[t][r] = -INFINITY;
                }
        }
        // online softmax: row max over 64 keys (4 tiles x 16 lanes of the quad)
        float mt[4];
#pragma unroll
        for (int r = 0; r < 4; ++r) {
            float v = fmaxf(fmaxf(sc[0][r], sc[1][r]), fmaxf(sc[2][r], sc[3][r]));
            v = fmaxf(v, __shfl_xor(v, 1, 16));
            v = fmaxf(v, __shfl_xor(v, 2, 16));
            v = fmaxf(v, __shfl_xor(v, 4, 16));
            v = fmaxf(v, __shfl_xor(v, 8, 16));
            mt[r] = v;
        }
        float alpha[4];
#pragma unroll
        for (int r = 0; r < 4; ++r) {
            const float mn = fmaxf(m_r[r], mt[r]);
            alpha[r] = __expf(m_r[r] - mn);
            m_r[r]   = mn;
        }
        float rs[4] = {0.f, 0.f, 0.f, 0.f};
#pragma unroll
        for (int t = 0; t < 4; ++t)
#pragma unroll
            for (int r = 0; r < 4; ++r) {
                const float p = __expf(sc[t][r] - m_r[r]);
                sc[t][r] = p;
                rs[r] += p;
            }
#pragma unroll
        for (int r = 0; r < 4; ++r) {
            float v = rs[r];
            v += __shfl_xor(v, 1, 16);
            v += __shfl_xor(v, 2, 16);
            v += __shfl_xor(v, 4, 16);
            v += __shfl_xor(v, 8, 16);
            l_r[r] = l_r[r] * alpha[r] + v;
        }
#pragma unroll
        for (int ot = 0; ot < 8; ++ot)
#pragma unroll
            for (int r = 0; r < 4; ++r) oacc[ot][r] *= alpha[r];

        // P: C-layout -> LDS -> A-layout (per-wave region)
#pragma unroll
        for (int t = 0; t < 4; ++t)
#pragma unroll
            for (int r = 0; r < 4; ++r)
                Ps[wave][(quad * 4 + r) * 64 + t * 16 + l16] = (__bf16)sc[t][r];
        __syncthreads();

        // O += P V
#pragma unroll
        for (int kk = 0; kk < 2; ++kk) {
            bf16x8 pf = *(const bf16x8*)(&Ps[wave][l16 * 64 + kk * 32 + quad * 8]);
#pragma unroll
            for (int ot = 0; ot < 8; ++ot) {
                bf16x8 vf = *(const bf16x8*)(Vs + (ot * 16 + l16) * 64 + kk * 32 + quad * 8);
                oacc[ot] = MFMA16(pf, vf, oacc[ot]);
            }
        }
    }

    // epilogue: O[b, s, h*128+d] = oacc / l
    const int b = bh >> 4, h = bh & (NH - 1);
#pragma unroll
    for (int ot = 0; ot < 8; ++ot)
#pragma unroll
        for (int r = 0; r < 4; ++r) {
            const int srow = q0 + wave * 16 + quad * 4 + r;
            const int d    = ot * 16 + l16;
            O[((size_t)(b * SEQ + srow)) * DM + h * HD + d] = (__bf16)(oacc[ot][r] / l_r[r]);
        }
}

// ---------------------------------------------------------------------------
extern "C" void kernel_launch(void* const* d_in, const int* in_sizes, int n_in,
                              void* d_out, int out_size, void* d_ws, size_t ws_size,
                              hipStream_t stream) {
    (void)in_sizes; (void)n_in; (void)out_size; (void)ws_size;
    const float* x  = (const float*)d_in[0];
    const float* Wq = (const float*)d_in[1];
    const float* bq = (const float*)d_in[2];
    const float* Wk = (const float*)d_in[3];
    const float* bk = (const float*)d_in[4];
    const float* Wv = (const float*)d_in[5];
    const float* bv = (const float*)d_in[6];
    const float* Wo = (const float*)d_in[7];
    const float* bo = (const float*)d_in[8];

    char* ws = (char*)d_ws;
    const size_t WT = (size_t)DM * DM * 2;      // 8 MB per transposed bf16 weight
    const size_t XB = (size_t)MROWS * DM * 2;   // 33.5 MB per bf16 activation
    __bf16* WqT = (__bf16*)(ws + 0 * WT);
    __bf16* WkT = (__bf16*)(ws + 1 * WT);
    __bf16* WvT = (__bf16*)(ws + 2 * WT);
    __bf16* WoT = (__bf16*)(ws + 3 * WT);
    __bf16* xb  = (__bf16*)(ws + 4 * WT + 0 * XB);
    __bf16* Qb  = (__bf16*)(ws + 4 * WT + 1 * XB);
    __bf16* Kb  = (__bf16*)(ws + 4 * WT + 2 * XB);
    __bf16* Vb  = (__bf16*)(ws + 4 * WT + 3 * XB);
    __bf16* Vtb = xb;   // x is dead after the three projections
    __bf16* Ob  = Vb;   // V is dead after the transpose

    const dim3 tb(32, 8);
    cvt_f32_bf16<<<8192, 256, 0, stream>>>(x, xb, (size_t)MROWS * DM);
    transpose_f32_to_bf16<<<dim3(64, 64), tb, 0, stream>>>(Wq, WqT, DM, DM);
    transpose_f32_to_bf16<<<dim3(64, 64), tb, 0, stream>>>(Wk, WkT, DM, DM);
    transpose_f32_to_bf16<<<dim3(64, 64), tb, 0, stream>>>(Wv, WvT, DM, DM);
    transpose_f32_to_bf16<<<dim3(64, 64), tb, 0, stream>>>(Wo, WoT, DM, DM);

    gemm_bt<0><<<dim3(64, 16), 256, 0, stream>>>(xb, WqT, bq, Qb);
    gemm_bt<0><<<dim3(64, 16), 256, 0, stream>>>(xb, WkT, bk, Kb);
    gemm_bt<0><<<dim3(64, 16), 256, 0, stream>>>(xb, WvT, bv, Vb);

    // V [B,H,S,D] -> Vt [B,H,D,S]
    transpose_bf16<<<dim3(HD / 32, SEQ / 32, 4 * NH), tb, 0, stream>>>(
        Vb, Vtb, SEQ, HD, (long)SEQ * HD, (long)SEQ * HD);

    fa_fwd<<<dim3(SEQ / 64, 4 * NH), 256, 0, stream>>>(Qb, Kb, Vtb, Ob);

    gemm_bt<1><<<dim3(64, 16), 256, 0, stream>>>(Ob, WoT, bo, (float*)d_out);
}

// Round 3
// 811.587 us; speedup vs baseline: 1.3284x; 1.3284x over previous
//
#include <hip/hip_runtime.h>
#include <hip/hip_bf16.h>
#include <math.h>

// Problem constants (CausalSelfAttention: B=4, S=2048, Dm=2048, H=16, Hd=128)
// Inputs/outputs are FP32 (per reference); compute in bf16 MFMA w/ fp32 accum.
#define SEQ   2048
#define DM    2048
#define NH    16
#define HD    128
#define MROWS 8192   // B*S

typedef __bf16 bf16x8 __attribute__((ext_vector_type(8)));
typedef float  f32x4  __attribute__((ext_vector_type(4)));

#define MFMA16(a, b, c) __builtin_amdgcn_mfma_f32_16x16x32_bf16((a), (b), (c), 0, 0, 0)

__device__ __forceinline__ void g2l16(const void* g, void* l) {
    __builtin_amdgcn_global_load_lds(
        (const __attribute__((address_space(1))) void*)g,
        (__attribute__((address_space(3))) void*)l, 16, 0, 0);
}

// ---------------------------------------------------------------------------
// Elementwise fp32 -> bf16 convert (8 elements / thread, 16B stores)
// ---------------------------------------------------------------------------
__global__ void cvt_f32_bf16(const float* __restrict__ src, __bf16* __restrict__ dst,
                             size_t n) {
    const size_t i0 = ((size_t)blockIdx.x * blockDim.x + threadIdx.x) * 8;
    if (i0 + 7 >= n) {
        for (size_t i = i0; i < n; ++i) dst[i] = (__bf16)src[i];
        return;
    }
    f32x4 a = *(const f32x4*)(src + i0);
    f32x4 b = *(const f32x4*)(src + i0 + 4);
    bf16x8 o;
#pragma unroll
    for (int j = 0; j < 4; ++j) { o[j] = (__bf16)a[j]; o[4 + j] = (__bf16)b[j]; }
    *(bf16x8*)(dst + i0) = o;
}

// ---------------------------------------------------------------------------
// Transpose + convert: dst[c][r] = (bf16)src[r][c], src fp32 [R,C]
// ---------------------------------------------------------------------------
__global__ void transpose_f32_to_bf16(const float* __restrict__ src,
                                      __bf16* __restrict__ dst, int R, int C) {
    __shared__ float t[32][33];
    const int r0 = blockIdx.y * 32, c0 = blockIdx.x * 32;
    for (int i = threadIdx.y; i < 32; i += 8)
        t[i][threadIdx.x] = src[(size_t)(r0 + i) * C + c0 + threadIdx.x];
    __syncthreads();
    for (int i = threadIdx.y; i < 32; i += 8)
        dst[(size_t)(c0 + i) * R + r0 + threadIdx.x] = (__bf16)t[threadIdx.x][i];
}

// ---------------------------------------------------------------------------
// Tiled transpose, bf16: dst[c][r] = src[r][c], batched over blockIdx.z
// ---------------------------------------------------------------------------
__global__ void transpose_bf16(const __bf16* __restrict__ src, __bf16* __restrict__ dst,
                               int R, int C, long sstride, long dstride) {
    __shared__ __bf16 t[32][33];
    src += (size_t)blockIdx.z * sstride;
    dst += (size_t)blockIdx.z * dstride;
    const int r0 = blockIdx.y * 32, c0 = blockIdx.x * 32;
    for (int i = threadIdx.y; i < 32; i += 8)
        t[i][threadIdx.x] = src[(size_t)(r0 + i) * C + c0 + threadIdx.x];
    __syncthreads();
    for (int i = threadIdx.y; i < 32; i += 8)
        dst[(size_t)(c0 + i) * R + r0 + threadIdx.x] = t[threadIdx.x][i];
}

// ---------------------------------------------------------------------------
// GEMM (m97 structure): C[M,N] = A[M,K] * Bt[N,K]^T + bias
// 128x128 tile, BK=32, 4 waves in 2x2, each wave 64x64 via 4x4 MFMA 16x16x32.
// MODE 0: fused QKV — Bt is [3*DM, DM] (WqT;WkT;WvT), writes bf16 [3][B,H,S,D].
// MODE 1: final proj — writes fp32 flat [M, DM].
// ---------------------------------------------------------------------------
template <int MODE>
__global__ __launch_bounds__(256) void gemm_bt(const __bf16* __restrict__ A,
                                               const __bf16* __restrict__ Bt,
                                               const float* __restrict__ b0,
                                               const float* __restrict__ b1,
                                               const float* __restrict__ b2,
                                               void* __restrict__ Cout_) {
    constexpr int K = DM;
    __shared__ __bf16 As[128 * 32];
    __shared__ __bf16 Bs[128 * 32];
    const int tid  = threadIdx.x;
    const int wave = tid >> 6, lane = tid & 63;
    const int quad = lane >> 4, l16 = lane & 15;
    const int bm = blockIdx.x * 128, bn = blockIdx.y * 128;
    const int wm = (wave >> 1) * 64, wn = (wave & 1) * 64;

    const int proj = (MODE == 0) ? (bn >> 11) : 0;               // wave-uniform
    const float* bias = (MODE == 0) ? (proj == 0 ? b0 : (proj == 1 ? b1 : b2)) : b0;

    f32x4 acc[4][4];
#pragma unroll
    for (int i = 0; i < 4; ++i)
#pragma unroll
        for (int j = 0; j < 4; ++j) acc[i][j] = (f32x4){0.f, 0.f, 0.f, 0.f};

    for (int k0 = 0; k0 < K; k0 += 32) {
        __syncthreads();
#pragma unroll
        for (int j = 0; j < 2; ++j) {
            const int region = wave + 4 * j;              // 0..7, 1KB regions
            const int row    = region * 16 + (lane >> 2); // 0..127
            const int kc     = lane & 3;                  // 16B chunk in 64B row
            g2l16(A  + (size_t)(bm + row) * K + k0 + kc * 8, As + region * 512);
            g2l16(Bt + (size_t)(bn + row) * K + k0 + kc * 8, Bs + region * 512);
        }
        __syncthreads();

        bf16x8 af[4], bf[4];
#pragma unroll
        for (int i = 0; i < 4; ++i)
            af[i] = *(const bf16x8*)(As + (wm + i * 16 + l16) * 32 + quad * 8);
#pragma unroll
        for (int j = 0; j < 4; ++j)
            bf[j] = *(const bf16x8*)(Bs + (wn + j * 16 + l16) * 32 + quad * 8);
#pragma unroll
        for (int i = 0; i < 4; ++i)
#pragma unroll
            for (int j = 0; j < 4; ++j) acc[i][j] = MFMA16(af[i], bf[j], acc[i][j]);
    }

#pragma unroll
    for (int i = 0; i < 4; ++i)
#pragma unroll
        for (int j = 0; j < 4; ++j)
#pragma unroll
            for (int r = 0; r < 4; ++r) {
                const int m  = bm + wm + i * 16 + quad * 4 + r;
                const int n3 = bn + wn + j * 16 + l16;
                const int n  = (MODE == 0) ? (n3 & (DM - 1)) : n3;
                const float v = acc[i][j][r] + bias[n];
                if (MODE == 0) {
                    const int b = m >> 11, s = m & (SEQ - 1);
                    const int h = n >> 7, d = n & (HD - 1);
                    ((__bf16*)Cout_)[(size_t)proj * MROWS * DM +
                                     ((size_t)((b * NH + h) * SEQ + s)) * HD + d] = (__bf16)v;
                } else {
                    ((float*)Cout_)[(size_t)m * DM + n] = v;
                }
            }
}

// ---------------------------------------------------------------------------
// Flash attention fwd, causal. Q,K: [B,H,S,D] bf16; Vt: [B,H,D,S] bf16.
// Block = 512 threads = 8 waves x 16 query rows = 128 queries; K-tiles of 64.
// Ks/Vs XOR-swizzled at 16B-chunk granularity (c' = c ^ (row&7)) so both the
// staging (global_load_lds, lane-contiguous LDS) and the strided fragment
// reads are LDS-bank-conflict-free. Ps padded to stride 72.
// Output O: [B,S,H*D] bf16 (row-major for the final GEMM).
// ---------------------------------------------------------------------------
__global__ __launch_bounds__(512) void fa_fwd(const __bf16* __restrict__ Q,
                                              const __bf16* __restrict__ Kg,
                                              const __bf16* __restrict__ Vt,
                                              __bf16* __restrict__ O) {
    __shared__ __bf16 Ks[64 * 128];    // [key][d] swizzled      16KB
    __shared__ __bf16 Vs[128 * 64];    // [d][key] swizzled      16KB
    __shared__ __bf16 Ps[8 * 16 * 72]; // per-wave P, stride 72  18KB
    const int tid  = threadIdx.x;
    const int wave = tid >> 6, lane = tid & 63;
    const int quad = lane >> 4, l16 = lane & 15;
    const int bh = blockIdx.y;         // b*NH + h
    const int q0 = blockIdx.x * 128;
    const int qrow0 = q0 + wave * 16;  // this wave's 16 query rows
    __bf16* Pw = Ps + wave * (16 * 72);

    // Q fragments in registers (row = qrow0 + l16)
    bf16x8 qf[4];
    const __bf16* qrow = Q + (size_t)(bh * SEQ + qrow0 + l16) * HD;
#pragma unroll
    for (int kc = 0; kc < 4; ++kc) qf[kc] = *(const bf16x8*)(qrow + kc * 32 + quad * 8);

    float m_r[4], l_r[4];
    f32x4 oacc[8];
#pragma unroll
    for (int r = 0; r < 4; ++r) { m_r[r] = -INFINITY; l_r[r] = 0.f; }
#pragma unroll
    for (int ot = 0; ot < 8; ++ot) oacc[ot] = (f32x4){0.f, 0.f, 0.f, 0.f};

    // scale * log2(e): softmax computed in base-2
    const float sl2 = 0.08838834764831845f * 1.4426950408889634f;

    const int ntiles = blockIdx.x * 2 + 2;   // keys up to q0+127
    for (int kt = 0; kt < ntiles; ++kt) {
        const int k0 = kt * 64;
        __syncthreads();  // protect Ks/Vs from overwrite while prev iter reads
        // ---- stage K (16 x 1KB regions) and Vt (16 x 1KB regions), swizzled
#pragma unroll
        for (int j = 0; j < 2; ++j) {
            const int reg  = wave * 2 + j;
            const int rowK = reg * 4 + (lane >> 4);           // 0..63
            const int cK   = (lane & 15) ^ (rowK & 7);        // 16B chunk 0..15
            g2l16(Kg + (size_t)(bh * SEQ + k0 + rowK) * HD + cK * 8, Ks + reg * 512);
            const int rowV = reg * 8 + (lane >> 3);           // 0..127
            const int cV   = (lane & 7) ^ (rowV & 7);         // 16B chunk 0..7
            g2l16(Vt + (size_t)(bh * HD + rowV) * SEQ + k0 + cV * 8, Vs + reg * 512);
        }
        __syncthreads();

        const bool active = (k0 <= qrow0 + 15);
        if (active) {
            // ---- S = Q K^T (base-2 scaled); C-layout row=quad*4+r, col=l16
            const int swz = l16 & 7;
            f32x4 sc[4];
#pragma unroll
            for (int t = 0; t < 4; ++t) {
                f32x4 a = (f32x4){0.f, 0.f, 0.f, 0.f};
#pragma unroll
                for (int kc = 0; kc < 4; ++kc) {
                    bf16x8 kf = *(const bf16x8*)(Ks + (t * 16 + l16) * 128 +
                                                 (((kc * 4 + quad) ^ swz) * 8));
                    a = MFMA16(qf[kc], kf, a);
                }
#pragma unroll
                for (int r = 0; r < 4; ++r) sc[t][r] = a[r] * sl2;
            }
            // ---- causal mask (only the last two tiles can touch the diagonal)
            if (kt >= ntiles - 2) {
#pragma unroll
                for (int t = 0; t < 4; ++t)
#pragma unroll
                    for (int r = 0; r < 4; ++r) {
                        const int key = k0 + t * 16 + l16;
                        const int qr  = qrow0 + quad * 4 + r;
                        if (key > qr) sc[t][r] = -INFINITY;
                    }
            }
            // ---- online softmax (base 2)
            float mt[4];
#pragma unroll
            for (int r = 0; r < 4; ++r) {
                float v = fmaxf(fmaxf(sc[0][r], sc[1][r]), fmaxf(sc[2][r], sc[3][r]));
                v = fmaxf(v, __shfl_xor(v, 1, 16));
                v = fmaxf(v, __shfl_xor(v, 2, 16));
                v = fmaxf(v, __shfl_xor(v, 4, 16));
                v = fmaxf(v, __shfl_xor(v, 8, 16));
                mt[r] = v;
            }
            float alpha[4];
#pragma unroll
            for (int r = 0; r < 4; ++r) {
                const float mn = fmaxf(m_r[r], mt[r]);
                alpha[r] = __builtin_amdgcn_exp2f(m_r[r] - mn);
                m_r[r]   = mn;
            }
            float rs[4] = {0.f, 0.f, 0.f, 0.f};
#pragma unroll
            for (int t = 0; t < 4; ++t)
#pragma unroll
                for (int r = 0; r < 4; ++r) {
                    const float p = __builtin_amdgcn_exp2f(sc[t][r] - m_r[r]);
                    sc[t][r] = p;
                    rs[r] += p;
                }
#pragma unroll
            for (int r = 0; r < 4; ++r) {
                float v = rs[r];
                v += __shfl_xor(v, 1, 16);
                v += __shfl_xor(v, 2, 16);
                v += __shfl_xor(v, 4, 16);
                v += __shfl_xor(v, 8, 16);
                l_r[r] = l_r[r] * alpha[r] + v;
            }
#pragma unroll
            for (int ot = 0; ot < 8; ++ot)
#pragma unroll
                for (int r = 0; r < 4; ++r) oacc[ot][r] *= alpha[r];

            // ---- P: C-layout -> LDS (wave-private, padded) -> A-layout
#pragma unroll
            for (int t = 0; t < 4; ++t)
#pragma unroll
                for (int r = 0; r < 4; ++r)
                    Pw[(quad * 4 + r) * 72 + t * 16 + l16] = (__bf16)sc[t][r];
            // (no barrier: Pw is wave-private; backend orders LDS w->r in-wave)

            // ---- O += P V
#pragma unroll
            for (int kk = 0; kk < 2; ++kk) {
                bf16x8 pf = *(const bf16x8*)(Pw + l16 * 72 + kk * 32 + quad * 8);
#pragma unroll
                for (int ot = 0; ot < 8; ++ot) {
                    bf16x8 vf = *(const bf16x8*)(Vs + (ot * 16 + l16) * 64 +
                                                 (((kk * 4 + quad) ^ swz) * 8));
                    oacc[ot] = MFMA16(pf, vf, oacc[ot]);
                }
            }
        }
    }

    // epilogue: O[b, s, h*128+d] = oacc / l
    const int b = bh >> 4, h = bh & (NH - 1);
#pragma unroll
    for (int ot = 0; ot < 8; ++ot)
#pragma unroll
        for (int r = 0; r < 4; ++r) {
            const int srow = qrow0 + quad * 4 + r;
            const int d    = ot * 16 + l16;
            O[((size_t)(b * SEQ + srow)) * DM + h * HD + d] = (__bf16)(oacc[ot][r] / l_r[r]);
        }
}

// ---------------------------------------------------------------------------
extern "C" void kernel_launch(void* const* d_in, const int* in_sizes, int n_in,
                              void* d_out, int out_size, void* d_ws, size_t ws_size,
                              hipStream_t stream) {
    (void)in_sizes; (void)n_in; (void)out_size; (void)ws_size;
    const float* x  = (const float*)d_in[0];
    const float* Wq = (const float*)d_in[1];
    const float* bq = (const float*)d_in[2];
    const float* Wk = (const float*)d_in[3];
    const float* bk = (const float*)d_in[4];
    const float* Wv = (const float*)d_in[5];
    const float* bv = (const float*)d_in[6];
    const float* Wo = (const float*)d_in[7];
    const float* bo = (const float*)d_in[8];

    char* ws = (char*)d_ws;
    const size_t WT = (size_t)DM * DM * 2;      // 8 MB per transposed bf16 weight
    const size_t XB = (size_t)MROWS * DM * 2;   // 33.5 MB per bf16 activation
    __bf16* WqT = (__bf16*)(ws + 0 * WT);       // WqT/WkT/WvT contiguous = fused Bt
    __bf16* WkT = (__bf16*)(ws + 1 * WT);
    __bf16* WvT = (__bf16*)(ws + 2 * WT);
    __bf16* WoT = (__bf16*)(ws + 3 * WT);
    __bf16* xb  = (__bf16*)(ws + 4 * WT + 0 * XB);
    __bf16* Qb  = (__bf16*)(ws + 4 * WT + 1 * XB);  // Qb/Kb/Vb contiguous
    __bf16* Vb  = (__bf16*)(ws + 4 * WT + 3 * XB);
    __bf16* Vtb = xb;   // x is dead after the QKV projection
    __bf16* Ob  = Vb;   // V is dead after the transpose

    const dim3 tb(32, 8);
    cvt_f32_bf16<<<8192, 256, 0, stream>>>(x, xb, (size_t)MROWS * DM);
    transpose_f32_to_bf16<<<dim3(64, 64), tb, 0, stream>>>(Wq, WqT, DM, DM);
    transpose_f32_to_bf16<<<dim3(64, 64), tb, 0, stream>>>(Wk, WkT, DM, DM);
    transpose_f32_to_bf16<<<dim3(64, 64), tb, 0, stream>>>(Wv, WvT, DM, DM);
    transpose_f32_to_bf16<<<dim3(64, 64), tb, 0, stream>>>(Wo, WoT, DM, DM);

    // Fused QKV projection: [8192,2048] x [2048,6144]
    gemm_bt<0><<<dim3(64, 48), 256, 0, stream>>>(xb, WqT, bq, bk, bv, Qb);

    // V [B,H,S,D] -> Vt [B,H,D,S]
    transpose_bf16<<<dim3(HD / 32, SEQ / 32, 4 * NH), tb, 0, stream>>>(
        Vb, Vtb, SEQ, HD, (long)SEQ * HD, (long)SEQ * HD);

    fa_fwd<<<dim3(SEQ / 128, 4 * NH), 512, 0, stream>>>(Qb, (const __bf16*)(ws + 4 * WT + 2 * XB), Vtb, Ob);

    gemm_bt<1><<<dim3(64, 16), 256, 0, stream>>>(Ob, WoT, bo, nullptr, nullptr, (float*)d_out);
}

// Round 4
// 791.842 us; speedup vs baseline: 1.3615x; 1.0249x over previous
//
#include <hip/hip_runtime.h>
#include <hip/hip_bf16.h>
#include <math.h>

// Problem constants (CausalSelfAttention: B=4, S=2048, Dm=2048, H=16, Hd=128)
// Inputs/outputs are FP32 (per reference); compute in bf16 MFMA w/ fp32 accum.
#define SEQ   2048
#define DM    2048
#define NH    16
#define HD    128
#define MROWS 8192   // B*S

typedef __bf16 bf16x8 __attribute__((ext_vector_type(8)));
typedef float  f32x4  __attribute__((ext_vector_type(4)));

#define MFMA16(a, b, c) __builtin_amdgcn_mfma_f32_16x16x32_bf16((a), (b), (c), 0, 0, 0)

__device__ __forceinline__ void g2l16(const void* g, void* l) {
    __builtin_amdgcn_global_load_lds(
        (const __attribute__((address_space(1))) void*)g,
        (__attribute__((address_space(3))) void*)l, 16, 0, 0);
}

// ---------------------------------------------------------------------------
// Elementwise fp32 -> bf16 convert (8 elements / thread, 16B stores)
// ---------------------------------------------------------------------------
__global__ void cvt_f32_bf16(const float* __restrict__ src, __bf16* __restrict__ dst,
                             size_t n) {
    const size_t i0 = ((size_t)blockIdx.x * blockDim.x + threadIdx.x) * 8;
    if (i0 + 7 >= n) {
        for (size_t i = i0; i < n; ++i) dst[i] = (__bf16)src[i];
        return;
    }
    f32x4 a = *(const f32x4*)(src + i0);
    f32x4 b = *(const f32x4*)(src + i0 + 4);
    bf16x8 o;
#pragma unroll
    for (int j = 0; j < 4; ++j) { o[j] = (__bf16)a[j]; o[4 + j] = (__bf16)b[j]; }
    *(bf16x8*)(dst + i0) = o;
}

// ---------------------------------------------------------------------------
// Fused transpose+convert of the 4 weights: dst[z][c][r] = (bf16)src_z[r][c]
// ---------------------------------------------------------------------------
__global__ void transpose4_f32_to_bf16(const float* __restrict__ s0,
                                       const float* __restrict__ s1,
                                       const float* __restrict__ s2,
                                       const float* __restrict__ s3,
                                       __bf16* __restrict__ dst) {
    __shared__ float t[32][33];
    const int z = blockIdx.z;
    const float* src = (z == 0) ? s0 : (z == 1) ? s1 : (z == 2) ? s2 : s3;
    __bf16* d = dst + (size_t)z * DM * DM;
    const int r0 = blockIdx.y * 32, c0 = blockIdx.x * 32;
    for (int i = threadIdx.y; i < 32; i += 8)
        t[i][threadIdx.x] = src[(size_t)(r0 + i) * DM + c0 + threadIdx.x];
    __syncthreads();
    for (int i = threadIdx.y; i < 32; i += 8)
        d[(size_t)(c0 + i) * DM + r0 + threadIdx.x] = (__bf16)t[threadIdx.x][i];
}

// ---------------------------------------------------------------------------
// Tiled transpose, bf16: dst[c][r] = src[r][c], batched over blockIdx.z
// ---------------------------------------------------------------------------
__global__ void transpose_bf16(const __bf16* __restrict__ src, __bf16* __restrict__ dst,
                               int R, int C, long sstride, long dstride) {
    __shared__ __bf16 t[32][33];
    src += (size_t)blockIdx.z * sstride;
    dst += (size_t)blockIdx.z * dstride;
    const int r0 = blockIdx.y * 32, c0 = blockIdx.x * 32;
    for (int i = threadIdx.y; i < 32; i += 8)
        t[i][threadIdx.x] = src[(size_t)(r0 + i) * C + c0 + threadIdx.x];
    __syncthreads();
    for (int i = threadIdx.y; i < 32; i += 8)
        dst[(size_t)(c0 + i) * R + r0 + threadIdx.x] = t[threadIdx.x][i];
}

// ---------------------------------------------------------------------------
// GEMM (m97 structure + XOR bank swizzle): C[M,N] = A[M,K]*Bt[N,K]^T + bias
// 128x128 tile, BK=32, 4 waves in 2x2, each wave 64x64 via 4x4 MFMA 16x16x32.
// LDS rows are 64B = 4 x 16B chunks; chunk stored at slot c^((row>>1)&3) so
// fragment reads hit all 8 bank groups (2-way = free) instead of 2 (8-way).
// MODE 0: fused QKV — Bt is [3*DM, DM] (WqT;WkT;WvT), writes bf16 [3][B,H,S,D].
// MODE 1: final proj — writes fp32 flat [M, DM].
// ---------------------------------------------------------------------------
template <int MODE>
__global__ __launch_bounds__(256) void gemm_bt(const __bf16* __restrict__ A,
                                               const __bf16* __restrict__ Bt,
                                               const float* __restrict__ b0,
                                               const float* __restrict__ b1,
                                               const float* __restrict__ b2,
                                               void* __restrict__ Cout_) {
    constexpr int K = DM;
    __shared__ __bf16 As[128 * 32];
    __shared__ __bf16 Bs[128 * 32];
    const int tid  = threadIdx.x;
    const int wave = tid >> 6, lane = tid & 63;
    const int quad = lane >> 4, l16 = lane & 15;
    const int bm = blockIdx.x * 128, bn = blockIdx.y * 128;
    const int wm = (wave >> 1) * 64, wn = (wave & 1) * 64;

    const int proj = (MODE == 0) ? (bn >> 11) : 0;               // wave-uniform
    const float* bias = (MODE == 0) ? (proj == 0 ? b0 : (proj == 1 ? b1 : b2)) : b0;

    f32x4 acc[4][4];
#pragma unroll
    for (int i = 0; i < 4; ++i)
#pragma unroll
        for (int j = 0; j < 4; ++j) acc[i][j] = (f32x4){0.f, 0.f, 0.f, 0.f};

    // staging source chunk swizzle: slot (lane&3) holds global chunk c
    const int srow = (lane >> 2);                  // row within 16-row region
    const int sc   = (lane & 3) ^ ((lane >> 3) & 3);
    // fragment read chunk swizzle
    const int rswz = (l16 >> 1) & 3;

    for (int k0 = 0; k0 < K; k0 += 32) {
        __syncthreads();
#pragma unroll
        for (int j = 0; j < 2; ++j) {
            const int region = wave + 4 * j;              // 0..7, 1KB regions
            const int row    = region * 16 + srow;        // 0..127
            g2l16(A  + (size_t)(bm + row) * K + k0 + sc * 8, As + region * 512);
            g2l16(Bt + (size_t)(bn + row) * K + k0 + sc * 8, Bs + region * 512);
        }
        __syncthreads();

        bf16x8 af[4], bf[4];
#pragma unroll
        for (int i = 0; i < 4; ++i)
            af[i] = *(const bf16x8*)(As + (wm + i * 16 + l16) * 32 + (quad ^ rswz) * 8);
#pragma unroll
        for (int j = 0; j < 4; ++j)
            bf[j] = *(const bf16x8*)(Bs + (wn + j * 16 + l16) * 32 + (quad ^ rswz) * 8);
#pragma unroll
        for (int i = 0; i < 4; ++i)
#pragma unroll
            for (int j = 0; j < 4; ++j) acc[i][j] = MFMA16(af[i], bf[j], acc[i][j]);
    }

#pragma unroll
    for (int i = 0; i < 4; ++i)
#pragma unroll
        for (int j = 0; j < 4; ++j)
#pragma unroll
            for (int r = 0; r < 4; ++r) {
                const int m  = bm + wm + i * 16 + quad * 4 + r;
                const int n3 = bn + wn + j * 16 + l16;
                const int n  = (MODE == 0) ? (n3 & (DM - 1)) : n3;
                const float v = acc[i][j][r] + bias[n];
                if (MODE == 0) {
                    const int b = m >> 11, s = m & (SEQ - 1);
                    const int h = n >> 7, d = n & (HD - 1);
                    ((__bf16*)Cout_)[(size_t)proj * MROWS * DM +
                                     ((size_t)((b * NH + h) * SEQ + s)) * HD + d] = (__bf16)v;
                } else {
                    ((float*)Cout_)[(size_t)m * DM + n] = v;
                }
            }
}

// ---------------------------------------------------------------------------
// Flash attention fwd, causal. Q,K: [B,H,S,D] bf16; Vt: [B,H,D,S] bf16.
// Block = 512 threads = 8 waves x 16 query rows = 128 queries; K-tiles of 64.
// Ks/Vs XOR-swizzled at 16B-chunk granularity (c' = c ^ (row&7)): conflict-free
// staging and fragment reads. Ps padded to stride 72. blockIdx.x is REVERSED
// so the heaviest (most k-tiles) blocks dispatch first (tail reduction).
// Output O: [B,S,H*D] bf16 (row-major for the final GEMM).
// ---------------------------------------------------------------------------
__global__ __launch_bounds__(512) void fa_fwd(const __bf16* __restrict__ Q,
                                              const __bf16* __restrict__ Kg,
                                              const __bf16* __restrict__ Vt,
                                              __bf16* __restrict__ O) {
    __shared__ __bf16 Ks[64 * 128];    // [key][d] swizzled      16KB
    __shared__ __bf16 Vs[128 * 64];    // [d][key] swizzled      16KB
    __shared__ __bf16 Ps[8 * 16 * 72]; // per-wave P, stride 72  18KB
    const int tid  = threadIdx.x;
    const int wave = tid >> 6, lane = tid & 63;
    const int quad = lane >> 4, l16 = lane & 15;
    const int bh = blockIdx.y;         // b*NH + h
    const int bx = gridDim.x - 1 - blockIdx.x;   // heavy blocks first
    const int q0 = bx * 128;
    const int qrow0 = q0 + wave * 16;  // this wave's 16 query rows
    __bf16* Pw = Ps + wave * (16 * 72);

    // Q fragments in registers (row = qrow0 + l16)
    bf16x8 qf[4];
    const __bf16* qrow = Q + (size_t)(bh * SEQ + qrow0 + l16) * HD;
#pragma unroll
    for (int kc = 0; kc < 4; ++kc) qf[kc] = *(const bf16x8*)(qrow + kc * 32 + quad * 8);

    float m_r[4], l_r[4];
    f32x4 oacc[8];
#pragma unroll
    for (int r = 0; r < 4; ++r) { m_r[r] = -INFINITY; l_r[r] = 0.f; }
#pragma unroll
    for (int ot = 0; ot < 8; ++ot) oacc[ot] = (f32x4){0.f, 0.f, 0.f, 0.f};

    // scale * log2(e): softmax computed in base-2
    const float sl2 = 0.08838834764831845f * 1.4426950408889634f;

    const int ntiles = bx * 2 + 2;     // keys up to q0+127
    for (int kt = 0; kt < ntiles; ++kt) {
        const int k0 = kt * 64;
        __syncthreads();  // protect Ks/Vs from overwrite while prev iter reads
        // ---- stage K (16 x 1KB regions) and Vt (16 x 1KB regions), swizzled
#pragma unroll
        for (int j = 0; j < 2; ++j) {
            const int reg  = wave * 2 + j;
            const int rowK = reg * 4 + (lane >> 4);           // 0..63
            const int cK   = (lane & 15) ^ (rowK & 7);        // 16B chunk 0..15
            g2l16(Kg + (size_t)(bh * SEQ + k0 + rowK) * HD + cK * 8, Ks + reg * 512);
            const int rowV = reg * 8 + (lane >> 3);           // 0..127
            const int cV   = (lane & 7) ^ (rowV & 7);         // 16B chunk 0..7
            g2l16(Vt + (size_t)(bh * HD + rowV) * SEQ + k0 + cV * 8, Vs + reg * 512);
        }
        __syncthreads();

        const bool active = (k0 <= qrow0 + 15);
        if (active) {
            // ---- S = Q K^T (base-2 scaled); C-layout row=quad*4+r, col=l16
            const int swz = l16 & 7;
            f32x4 sc[4];
#pragma unroll
            for (int t = 0; t < 4; ++t) {
                f32x4 a = (f32x4){0.f, 0.f, 0.f, 0.f};
#pragma unroll
                for (int kc = 0; kc < 4; ++kc) {
                    bf16x8 kf = *(const bf16x8*)(Ks + (t * 16 + l16) * 128 +
                                                 (((kc * 4 + quad) ^ swz) * 8));
                    a = MFMA16(qf[kc], kf, a);
                }
#pragma unroll
                for (int r = 0; r < 4; ++r) sc[t][r] = a[r] * sl2;
            }
            // ---- causal mask (only the last two tiles can touch the diagonal)
            if (kt >= ntiles - 2) {
#pragma unroll
                for (int t = 0; t < 4; ++t)
#pragma unroll
                    for (int r = 0; r < 4; ++r) {
                        const int key = k0 + t * 16 + l16;
                        const int qr  = qrow0 + quad * 4 + r;
                        if (key > qr) sc[t][r] = -INFINITY;
                    }
            }
            // ---- online softmax (base 2)
            float mt[4];
#pragma unroll
            for (int r = 0; r < 4; ++r) {
                float v = fmaxf(fmaxf(sc[0][r], sc[1][r]), fmaxf(sc[2][r], sc[3][r]));
                v = fmaxf(v, __shfl_xor(v, 1, 16));
                v = fmaxf(v, __shfl_xor(v, 2, 16));
                v = fmaxf(v, __shfl_xor(v, 4, 16));
                v = fmaxf(v, __shfl_xor(v, 8, 16));
                mt[r] = v;
            }
            float alpha[4];
#pragma unroll
            for (int r = 0; r < 4; ++r) {
                const float mn = fmaxf(m_r[r], mt[r]);
                alpha[r] = __builtin_amdgcn_exp2f(m_r[r] - mn);
                m_r[r]   = mn;
            }
            float rs[4] = {0.f, 0.f, 0.f, 0.f};
#pragma unroll
            for (int t = 0; t < 4; ++t)
#pragma unroll
                for (int r = 0; r < 4; ++r) {
                    const float p = __builtin_amdgcn_exp2f(sc[t][r] - m_r[r]);
                    sc[t][r] = p;
                    rs[r] += p;
                }
#pragma unroll
            for (int r = 0; r < 4; ++r) {
                float v = rs[r];
                v += __shfl_xor(v, 1, 16);
                v += __shfl_xor(v, 2, 16);
                v += __shfl_xor(v, 4, 16);
                v += __shfl_xor(v, 8, 16);
                l_r[r] = l_r[r] * alpha[r] + v;
            }
#pragma unroll
            for (int ot = 0; ot < 8; ++ot)
#pragma unroll
                for (int r = 0; r < 4; ++r) oacc[ot][r] *= alpha[r];

            // ---- P: C-layout -> LDS (wave-private, padded) -> A-layout
#pragma unroll
            for (int t = 0; t < 4; ++t)
#pragma unroll
                for (int r = 0; r < 4; ++r)
                    Pw[(quad * 4 + r) * 72 + t * 16 + l16] = (__bf16)sc[t][r];
            // (no barrier: Pw is wave-private; backend orders LDS w->r in-wave)

            // ---- O += P V
#pragma unroll
            for (int kk = 0; kk < 2; ++kk) {
                bf16x8 pf = *(const bf16x8*)(Pw + l16 * 72 + kk * 32 + quad * 8);
#pragma unroll
                for (int ot = 0; ot < 8; ++ot) {
                    bf16x8 vf = *(const bf16x8*)(Vs + (ot * 16 + l16) * 64 +
                                                 (((kk * 4 + quad) ^ swz) * 8));
                    oacc[ot] = MFMA16(pf, vf, oacc[ot]);
                }
            }
        }
    }

    // epilogue: O[b, s, h*128+d] = oacc / l
    const int b = bh >> 4, h = bh & (NH - 1);
#pragma unroll
    for (int ot = 0; ot < 8; ++ot)
#pragma unroll
        for (int r = 0; r < 4; ++r) {
            const int srow = qrow0 + quad * 4 + r;
            const int d    = ot * 16 + l16;
            O[((size_t)(b * SEQ + srow)) * DM + h * HD + d] = (__bf16)(oacc[ot][r] / l_r[r]);
        }
}

// ---------------------------------------------------------------------------
extern "C" void kernel_launch(void* const* d_in, const int* in_sizes, int n_in,
                              void* d_out, int out_size, void* d_ws, size_t ws_size,
                              hipStream_t stream) {
    (void)in_sizes; (void)n_in; (void)out_size; (void)ws_size;
    const float* x  = (const float*)d_in[0];
    const float* Wq = (const float*)d_in[1];
    const float* bq = (const float*)d_in[2];
    const float* Wk = (const float*)d_in[3];
    const float* bk = (const float*)d_in[4];
    const float* Wv = (const float*)d_in[5];
    const float* bv = (const float*)d_in[6];
    const float* Wo = (const float*)d_in[7];
    const float* bo = (const float*)d_in[8];

    char* ws = (char*)d_ws;
    const size_t WT = (size_t)DM * DM * 2;      // 8 MB per transposed bf16 weight
    const size_t XB = (size_t)MROWS * DM * 2;   // 33.5 MB per bf16 activation
    __bf16* WTs = (__bf16*)ws;                  // WqT;WkT;WvT;WoT contiguous
    __bf16* WoT = (__bf16*)(ws + 3 * WT);
    __bf16* xb  = (__bf16*)(ws + 4 * WT + 0 * XB);
    __bf16* Qb  = (__bf16*)(ws + 4 * WT + 1 * XB);  // Qb/Kb/Vb contiguous
    __bf16* Kb  = (__bf16*)(ws + 4 * WT + 2 * XB);
    __bf16* Vb  = (__bf16*)(ws + 4 * WT + 3 * XB);
    __bf16* Vtb = xb;   // x is dead after the QKV projection
    __bf16* Ob  = Vb;   // V is dead after the transpose

    const dim3 tb(32, 8);
    cvt_f32_bf16<<<8192, 256, 0, stream>>>(x, xb, (size_t)MROWS * DM);
    transpose4_f32_to_bf16<<<dim3(64, 64, 4), tb, 0, stream>>>(Wq, Wk, Wv, Wo, WTs);

    // Fused QKV projection: [8192,2048] x [2048,6144]
    gemm_bt<0><<<dim3(64, 48), 256, 0, stream>>>(xb, WTs, bq, bk, bv, Qb);

    // V [B,H,S,D] -> Vt [B,H,D,S]
    transpose_bf16<<<dim3(HD / 32, SEQ / 32, 4 * NH), tb, 0, stream>>>(
        Vb, Vtb, SEQ, HD, (long)SEQ * HD, (long)SEQ * HD);

    fa_fwd<<<dim3(SEQ / 128, 4 * NH), 512, 0, stream>>>(Qb, Kb, Vtb, Ob);

    gemm_bt<1><<<dim3(64, 16), 256, 0, stream>>>(Ob, WoT, bo, nullptr, nullptr, (float*)d_out);
}

// Round 5
// 728.287 us; speedup vs baseline: 1.4803x; 1.0873x over previous
//
#include <hip/hip_runtime.h>
#include <hip/hip_bf16.h>
#include <math.h>

// Problem constants (CausalSelfAttention: B=4, S=2048, Dm=2048, H=16, Hd=128)
// Inputs/outputs are FP32 (per reference); compute in bf16 MFMA w/ fp32 accum.
#define SEQ   2048
#define DM    2048
#define NH    16
#define HD    128
#define MROWS 8192   // B*S

typedef __bf16 bf16x8 __attribute__((ext_vector_type(8)));
typedef __bf16 bf16x4 __attribute__((ext_vector_type(4)));
typedef float  f32x4  __attribute__((ext_vector_type(4)));

#define MFMA16(a, b, c) __builtin_amdgcn_mfma_f32_16x16x32_bf16((a), (b), (c), 0, 0, 0)

__device__ __forceinline__ void g2l16(const void* g, void* l) {
    __builtin_amdgcn_global_load_lds(
        (const __attribute__((address_space(1))) void*)g,
        (__attribute__((address_space(3))) void*)l, 16, 0, 0);
}

// ---------------------------------------------------------------------------
// Fused prep: blocks [0,16384): transpose+convert the 4 weights
//             blocks [16384, 24576): elementwise x fp32->bf16
// All blocks are (32,8) = 256 threads.
// ---------------------------------------------------------------------------
__global__ void prep_fused(const float* __restrict__ x,
                           const float* __restrict__ s0,
                           const float* __restrict__ s1,
                           const float* __restrict__ s2,
                           const float* __restrict__ s3,
                           __bf16* __restrict__ xb,
                           __bf16* __restrict__ wdst) {
    const int bx = blockIdx.x;
    if (bx < 16384) {
        __shared__ float t[32][33];
        const int z = bx >> 12, rem = bx & 4095;
        const float* src = (z == 0) ? s0 : (z == 1) ? s1 : (z == 2) ? s2 : s3;
        __bf16* d = wdst + (size_t)z * DM * DM;
        const int c0 = (rem & 63) * 32, r0 = (rem >> 6) * 32;
        for (int i = threadIdx.y; i < 32; i += 8)
            t[i][threadIdx.x] = src[(size_t)(r0 + i) * DM + c0 + threadIdx.x];
        __syncthreads();
        for (int i = threadIdx.y; i < 32; i += 8)
            d[(size_t)(c0 + i) * DM + r0 + threadIdx.x] = (__bf16)t[threadIdx.x][i];
    } else {
        const int tid = threadIdx.y * 32 + threadIdx.x;
        const size_t i0 = (((size_t)(bx - 16384)) * 256 + tid) * 8;
        if (i0 + 8 <= (size_t)MROWS * DM) {
            f32x4 a = *(const f32x4*)(x + i0);
            f32x4 b = *(const f32x4*)(x + i0 + 4);
            bf16x8 o;
#pragma unroll
            for (int j = 0; j < 4; ++j) { o[j] = (__bf16)a[j]; o[4 + j] = (__bf16)b[j]; }
            *(bf16x8*)(xb + i0) = o;
        }
    }
}

// ---------------------------------------------------------------------------
// Tiled transpose, bf16: dst[c][r] = src[r][c], batched over blockIdx.z
// ---------------------------------------------------------------------------
__global__ void transpose_bf16(const __bf16* __restrict__ src, __bf16* __restrict__ dst,
                               int R, int C, long sstride, long dstride) {
    __shared__ __bf16 t[32][33];
    src += (size_t)blockIdx.z * sstride;
    dst += (size_t)blockIdx.z * dstride;
    const int r0 = blockIdx.y * 32, c0 = blockIdx.x * 32;
    for (int i = threadIdx.y; i < 32; i += 8)
        t[i][threadIdx.x] = src[(size_t)(r0 + i) * C + c0 + threadIdx.x];
    __syncthreads();
    for (int i = threadIdx.y; i < 32; i += 8)
        dst[(size_t)(c0 + i) * R + r0 + threadIdx.x] = t[threadIdx.x][i];
}

// ---------------------------------------------------------------------------
// GEMM (m97 structure + XOR bank swizzle): C[M,N] = A[M,K]*Bt[N,K]^T + bias
// 128x128 tile, BK=32, 4 waves in 2x2, each wave 64x64 via 4x4 MFMA 16x16x32.
// MODE 0: fused QKV — Bt is [3*DM, DM] (WqT;WkT;WvT), writes bf16 [3][B,H,S,D].
// MODE 1: final proj — writes fp32 flat [M, DM].
// ---------------------------------------------------------------------------
template <int MODE>
__global__ __launch_bounds__(256) void gemm_bt(const __bf16* __restrict__ A,
                                               const __bf16* __restrict__ Bt,
                                               const float* __restrict__ b0,
                                               const float* __restrict__ b1,
                                               const float* __restrict__ b2,
                                               void* __restrict__ Cout_) {
    constexpr int K = DM;
    __shared__ __bf16 As[128 * 32];
    __shared__ __bf16 Bs[128 * 32];
    const int tid  = threadIdx.x;
    const int wave = tid >> 6, lane = tid & 63;
    const int quad = lane >> 4, l16 = lane & 15;
    const int bm = blockIdx.x * 128, bn = blockIdx.y * 128;
    const int wm = (wave >> 1) * 64, wn = (wave & 1) * 64;

    const int proj = (MODE == 0) ? (bn >> 11) : 0;               // wave-uniform
    const float* bias = (MODE == 0) ? (proj == 0 ? b0 : (proj == 1 ? b1 : b2)) : b0;

    f32x4 acc[4][4];
#pragma unroll
    for (int i = 0; i < 4; ++i)
#pragma unroll
        for (int j = 0; j < 4; ++j) acc[i][j] = (f32x4){0.f, 0.f, 0.f, 0.f};

    // staging source chunk swizzle: slot (lane&3) holds global chunk c
    const int srow = (lane >> 2);                  // row within 16-row region
    const int sc   = (lane & 3) ^ ((lane >> 3) & 3);
    // fragment read chunk swizzle
    const int rswz = (l16 >> 1) & 3;

    for (int k0 = 0; k0 < K; k0 += 32) {
        __syncthreads();
#pragma unroll
        for (int j = 0; j < 2; ++j) {
            const int region = wave + 4 * j;              // 0..7, 1KB regions
            const int row    = region * 16 + srow;        // 0..127
            g2l16(A  + (size_t)(bm + row) * K + k0 + sc * 8, As + region * 512);
            g2l16(Bt + (size_t)(bn + row) * K + k0 + sc * 8, Bs + region * 512);
        }
        __syncthreads();

        bf16x8 af[4], bf[4];
#pragma unroll
        for (int i = 0; i < 4; ++i)
            af[i] = *(const bf16x8*)(As + (wm + i * 16 + l16) * 32 + (quad ^ rswz) * 8);
#pragma unroll
        for (int j = 0; j < 4; ++j)
            bf[j] = *(const bf16x8*)(Bs + (wn + j * 16 + l16) * 32 + (quad ^ rswz) * 8);
#pragma unroll
        for (int i = 0; i < 4; ++i)
#pragma unroll
            for (int j = 0; j < 4; ++j) acc[i][j] = MFMA16(af[i], bf[j], acc[i][j]);
    }

#pragma unroll
    for (int i = 0; i < 4; ++i)
#pragma unroll
        for (int j = 0; j < 4; ++j)
#pragma unroll
            for (int r = 0; r < 4; ++r) {
                const int m  = bm + wm + i * 16 + quad * 4 + r;
                const int n3 = bn + wn + j * 16 + l16;
                const int n  = (MODE == 0) ? (n3 & (DM - 1)) : n3;
                const float v = acc[i][j][r] + bias[n];
                if (MODE == 0) {
                    const int b = m >> 11, s = m & (SEQ - 1);
                    const int h = n >> 7, d = n & (HD - 1);
                    ((__bf16*)Cout_)[(size_t)proj * MROWS * DM +
                                     ((size_t)((b * NH + h) * SEQ + s)) * HD + d] = (__bf16)v;
                } else {
                    ((float*)Cout_)[(size_t)m * DM + n] = v;
                }
            }
}

// ---------------------------------------------------------------------------
// Flash attention fwd, causal — TRANSPOSED-S formulation.
// Q,K: [B,H,S,D] bf16; Vt: [B,H,D,S] bf16. Block = 8 waves x 16 q-rows = 128 q.
// S^T = K·Q^T (operand swap): C-layout gives lane=query, regs=keys, so
// softmax reduces are 15 in-reg ops + 2 shuffles, m/l/alpha are per-lane
// scalars, and P^T packs into ds_write_b64 / reads back as ds_read_b128.
// PV computes O^T = V^T·P^T straight from the Vs[d][key] layout.
// Ks/Vs XOR-swizzled (chunk c -> slot c^(row&7)): conflict-free staging+reads.
// blockIdx.x REVERSED so heavy (many-k-tile) blocks dispatch first.
// ---------------------------------------------------------------------------
__global__ __launch_bounds__(512) void fa_fwd(const __bf16* __restrict__ Q,
                                              const __bf16* __restrict__ Kg,
                                              const __bf16* __restrict__ Vt,
                                              __bf16* __restrict__ O) {
    __shared__ __bf16 Ks[64 * 128];     // [key][d] swizzled       16KB
    __shared__ __bf16 Vs[128 * 64];     // [d][key] swizzled       16KB
    __shared__ __bf16 Pt[8][16 * 72];   // per-wave P^T as [q][key] 18KB
    const int tid  = threadIdx.x;
    const int wave = tid >> 6, lane = tid & 63;
    const int quad = lane >> 4, l16 = lane & 15;
    const int bh = blockIdx.y;          // b*NH + h
    const int bx = gridDim.x - 1 - blockIdx.x;
    const int q0 = bx * 128;
    const int qrow0 = q0 + wave * 16;   // this wave's 16 query rows
    __bf16* Pw = &Pt[wave][0];

    // Q B-fragments in registers: B[k=d][n=q]: lane holds Q[qrow0+l16][kc*32+quad*8..+7]
    bf16x8 qf[4];
    const __bf16* qrow = Q + (size_t)(bh * SEQ + qrow0 + l16) * HD;
#pragma unroll
    for (int kc = 0; kc < 4; ++kc) qf[kc] = *(const bf16x8*)(qrow + kc * 32 + quad * 8);

    float m_q = -INFINITY, l_q = 0.f;   // per-lane: query q = qrow0 + l16
    f32x4 oacc[8];                      // O^T: d = ot*16 + quad*4 + r, q = l16
#pragma unroll
    for (int ot = 0; ot < 8; ++ot) oacc[ot] = (f32x4){0.f, 0.f, 0.f, 0.f};

    const float sl2 = 0.08838834764831845f * 1.4426950408889634f;  // scale*log2(e)

    const int ntiles = bx * 2 + 2;      // keys up to q0+127
    for (int kt = 0; kt < ntiles; ++kt) {
        const int k0 = kt * 64;
        __syncthreads();  // protect Ks/Vs from overwrite while prev iter reads
        // ---- stage K and Vt (16 x 1KB regions each), swizzled
#pragma unroll
        for (int j = 0; j < 2; ++j) {
            const int reg  = wave * 2 + j;
            const int rowK = reg * 4 + (lane >> 4);           // 0..63
            const int cK   = (lane & 15) ^ (rowK & 7);        // 16B chunk 0..15
            g2l16(Kg + (size_t)(bh * SEQ + k0 + rowK) * HD + cK * 8, Ks + reg * 512);
            const int rowV = reg * 8 + (lane >> 3);           // 0..127
            const int cV   = (lane & 7) ^ (rowV & 7);         // 16B chunk 0..7
            g2l16(Vt + (size_t)(bh * HD + rowV) * SEQ + k0 + cV * 8, Vs + reg * 512);
        }
        __syncthreads();

        if (k0 <= qrow0 + 15) {         // wave has unmasked work in this tile
            const int swz = l16 & 7;
            // ---- S^T = K Q^T (scaled): tile t rows = keys t*16+quad*4+r, col q=l16
            f32x4 st[4];
#pragma unroll
            for (int t = 0; t < 4; ++t) {
                f32x4 a = (f32x4){0.f, 0.f, 0.f, 0.f};
#pragma unroll
                for (int kc = 0; kc < 4; ++kc) {
                    bf16x8 kf = *(const bf16x8*)(Ks + (t * 16 + l16) * 128 +
                                                 (((kc * 4 + quad) ^ swz) * 8));
                    a = MFMA16(kf, qf[kc], a);        // A = K, B = Q
                }
#pragma unroll
                for (int r = 0; r < 4; ++r) st[t][r] = a[r] * sl2;
            }
            // ---- causal mask (diagonal only lives in the last two tiles)
            if (kt >= ntiles - 2) {
                const int q = qrow0 + l16;
#pragma unroll
                for (int t = 0; t < 4; ++t)
#pragma unroll
                    for (int r = 0; r < 4; ++r) {
                        const int key = k0 + t * 16 + quad * 4 + r;
                        if (key > q) st[t][r] = -INFINITY;
                    }
            }
            // ---- online softmax over keys (regs + quads)
            float vm = st[0][0];
#pragma unroll
            for (int t = 0; t < 4; ++t)
#pragma unroll
                for (int r = 0; r < 4; ++r) vm = fmaxf(vm, st[t][r]);
            vm = fmaxf(vm, __shfl_xor(vm, 16));
            vm = fmaxf(vm, __shfl_xor(vm, 32));
            const float mn = fmaxf(m_q, vm);
            const float alpha = __builtin_amdgcn_exp2f(m_q - mn);
            m_q = mn;
            float ps = 0.f;
#pragma unroll
            for (int t = 0; t < 4; ++t)
#pragma unroll
                for (int r = 0; r < 4; ++r) {
                    const float p = __builtin_amdgcn_exp2f(st[t][r] - mn);
                    st[t][r] = p;
                    ps += p;
                }
            ps += __shfl_xor(ps, 16);
            ps += __shfl_xor(ps, 32);
            l_q = l_q * alpha + ps;
#pragma unroll
            for (int ot = 0; ot < 8; ++ot)
#pragma unroll
                for (int r = 0; r < 4; ++r) oacc[ot][r] *= alpha;

            // ---- P^T rows: lane writes 4 consecutive keys at row q=l16 (b64)
#pragma unroll
            for (int t = 0; t < 4; ++t) {
                bf16x4 pk;
#pragma unroll
                for (int r = 0; r < 4; ++r) pk[r] = (__bf16)st[t][r];
                *(bf16x4*)(Pw + l16 * 72 + t * 16 + quad * 4) = pk;
            }
            // (Pw wave-private; compiler inserts lgkmcnt before dependent reads)

            // ---- O^T += V^T P^T
#pragma unroll
            for (int kk = 0; kk < 2; ++kk) {
                bf16x8 pf = *(const bf16x8*)(Pw + l16 * 72 + kk * 32 + quad * 8);
#pragma unroll
                for (int ot = 0; ot < 8; ++ot) {
                    bf16x8 vf = *(const bf16x8*)(Vs + (ot * 16 + l16) * 64 +
                                                 (((kk * 4 + quad) ^ swz) * 8));
                    oacc[ot] = MFMA16(vf, pf, oacc[ot]);   // A = V^T, B = P^T
                }
            }
        }
    }

    // epilogue: O[b, s=qrow0+l16, h*128 + d], d = ot*16 + quad*4 + r (8B stores)
    const int b = bh >> 4, h = bh & (NH - 1);
    const float inv = 1.0f / l_q;
    __bf16* orow = O + ((size_t)(b * SEQ + qrow0 + l16)) * DM + h * HD;
#pragma unroll
    for (int ot = 0; ot < 8; ++ot) {
        bf16x4 ov;
#pragma unroll
        for (int r = 0; r < 4; ++r) ov[r] = (__bf16)(oacc[ot][r] * inv);
        *(bf16x4*)(orow + ot * 16 + quad * 4) = ov;
    }
}

// ---------------------------------------------------------------------------
extern "C" void kernel_launch(void* const* d_in, const int* in_sizes, int n_in,
                              void* d_out, int out_size, void* d_ws, size_t ws_size,
                              hipStream_t stream) {
    (void)in_sizes; (void)n_in; (void)out_size; (void)ws_size;
    const float* x  = (const float*)d_in[0];
    const float* Wq = (const float*)d_in[1];
    const float* bq = (const float*)d_in[2];
    const float* Wk = (const float*)d_in[3];
    const float* bk = (const float*)d_in[4];
    const float* Wv = (const float*)d_in[5];
    const float* bv = (const float*)d_in[6];
    const float* Wo = (const float*)d_in[7];
    const float* bo = (const float*)d_in[8];

    char* ws = (char*)d_ws;
    const size_t WT = (size_t)DM * DM * 2;      // 8 MB per transposed bf16 weight
    const size_t XB = (size_t)MROWS * DM * 2;   // 33.5 MB per bf16 activation
    __bf16* WTs = (__bf16*)ws;                  // WqT;WkT;WvT;WoT contiguous
    __bf16* WoT = (__bf16*)(ws + 3 * WT);
    __bf16* xb  = (__bf16*)(ws + 4 * WT + 0 * XB);
    __bf16* Qb  = (__bf16*)(ws + 4 * WT + 1 * XB);  // Qb/Kb/Vb contiguous
    __bf16* Kb  = (__bf16*)(ws + 4 * WT + 2 * XB);
    __bf16* Vb  = (__bf16*)(ws + 4 * WT + 3 * XB);
    __bf16* Vtb = xb;   // x is dead after the QKV projection
    __bf16* Ob  = Vb;   // V is dead after the transpose

    const dim3 tb(32, 8);
    prep_fused<<<16384 + 8192, tb, 0, stream>>>(x, Wq, Wk, Wv, Wo, xb, WTs);

    // Fused QKV projection: [8192,2048] x [2048,6144]
    gemm_bt<0><<<dim3(64, 48), 256, 0, stream>>>(xb, WTs, bq, bk, bv, Qb);

    // V [B,H,S,D] -> Vt [B,H,D,S]
    transpose_bf16<<<dim3(HD / 32, SEQ / 32, 4 * NH), tb, 0, stream>>>(
        Vb, Vtb, SEQ, HD, (long)SEQ * HD, (long)SEQ * HD);

    fa_fwd<<<dim3(SEQ / 128, 4 * NH), 512, 0, stream>>>(Qb, Kb, Vtb, Ob);

    gemm_bt<1><<<dim3(64, 16), 256, 0, stream>>>(Ob, WoT, bo, nullptr, nullptr, (float*)d_out);
}